// Round 11
// baseline (163.191 us; speedup 1.0000x reference)
//
#include <hip/hip_runtime.h>
#include <math.h>

#define EPSF 1e-7f
constexpr int NN  = 100;   // nodes per graph
constexpr int DEG = 99;    // fully-connected: deg = NN-1
constexpr int IN  = 6;
constexpr int H   = 128;
constexpr int G   = 4;     // nodes per block
constexpr float INV_PI = 0.3183098861837907f;

typedef __attribute__((ext_vector_type(4))) _Float16 half4;
typedef __attribute__((ext_vector_type(8))) _Float16 half8;
typedef __attribute__((ext_vector_type(4))) float f32x4;

constexpr int XST = 144;   // fp16 staging stride (288B rows: 16B-aligned)

__device__ __forceinline__ float clampf(float x, float lo, float hi) {
    return fminf(fmaxf(x, lo), hi);
}
__device__ __forceinline__ float fast_sig(float x) {
    return __builtin_amdgcn_rcpf(1.f + __expf(-x));
}
// fast atan2: octant-reduced minimax poly, ~1e-5 rad
__device__ __forceinline__ float fast_atan2(float y, float x) {
    float ax = fabsf(x), ay = fabsf(y);
    float mx = fmaxf(ax, ay), mn = fminf(ax, ay);
    float r = mn * __builtin_amdgcn_rcpf(fmaxf(mx, 1e-35f));
    float r2 = r * r;
    float p = fmaf(r2, -0.01172120f, 0.05265332f);
    p = fmaf(r2, p, -0.11643287f);
    p = fmaf(r2, p, 0.19354346f);
    p = fmaf(r2, p, -0.33262347f);
    p = fmaf(r2, p, 0.99997726f);
    float t = r * p;
    t = (ay > ax) ? (1.5707963267948966f - t) : t;
    t = (x < 0.f) ? (3.14159265358979323f - t) : t;
    return copysignf(t, y);
}
__device__ __forceinline__ float fast_asin(float z) {
    return fast_atan2(z, sqrtf(fmaxf(0.f, (1.f - z) * (1.f + z))));
}
__device__ __forceinline__ float fast_acos(float z) {
    return fast_atan2(sqrtf(fmaxf(0.f, (1.f - z) * (1.f + z))), z);
}
__device__ __forceinline__ void vel_to_R(float vx, float vy, float vz, float* R) {
    float rho = sqrtf(vx * vx + vy * vy + vz * vz);
    float rxy = sqrtf(vx * vx + vy * vy);
    float inv = __builtin_amdgcn_rcpf(rxy);
    bool big = rxy > 1e-30f;
    float ct = big ? vx * inv : 1.f;
    float st = big ? vy * inv : 0.f;
    float cp = clampf(vz * __builtin_amdgcn_rcpf(rho + EPSF), -1.f, 1.f);
    float sp = sqrtf(fmaxf(0.f, 1.f - cp * cp));
    R[0] = cp * ct; R[1] = -st; R[2] = sp * ct;
    R[3] = cp * st; R[4] = ct;  R[5] = sp * st;
    R[6] = -sp;     R[7] = 0.f; R[8] = cp;
}

// ---------------- Kernel A: weights -> fp16 MFMA fragments in ws.
__global__ void conv_w(const float* __restrict__ W1, const float* __restrict__ W2,
                       const float* __restrict__ W3, const float* __restrict__ W4,
                       half4* __restrict__ w1f, half8* __restrict__ wmlp) {
    int t = blockIdx.x * blockDim.x + threadIdx.x;
    if (t >= 104 * 64) return;
    int L = t & 63, f = t >> 6;
    int m = L & 15, qd = L >> 4;
    if (f < 8) {                          // W1 fragments (K=16, k<12 live)
        int n = f * 16 + m;
        half4 v;
#pragma unroll
        for (int j = 0; j < 4; ++j) {
            int k = qd * 4 + j;
            v[j] = (k < 12) ? (_Float16)W1[k * H + n] : (_Float16)0.f;
        }
        w1f[f * 64 + L] = v;
    } else {                              // node-MLP weight fragments (K=32)
        int ff = f - 8;
        int layer = ff >> 5, rest = ff & 31;
        int kt = rest >> 3, nt = rest & 7;
        const float* W = (layer == 0) ? W2 : (layer == 1) ? W3 : W4;
        int n = nt * 16 + m;
        half8 v;
#pragma unroll
        for (int j = 0; j < 8; ++j)
            v[j] = (_Float16)W[(kt * 32 + qd * 8 + j) * H + n];
        wmlp[((layer * 4 + kt) * 8 + nt) * 64 + L] = v;
    }
}

// ---------------- Kernel B: fully fused LoCS layer. One block = 4 nodes.
// R9 feature path (global sender loads, per-job vel_to_R, broadcast rmF —
// conflict-free; R10's sR[100] stride-16 table caused 32-way LDS conflicts).
// R10 consumer (uniform 7-tile loop, pad rows cancelled via -13*silu(bias),
// batched 16-exp silu). Plain launch_bounds: high VGPR => silu-chain ILP.
__global__ __launch_bounds__(128)
void locs_fused(const float* __restrict__ in,
                const float* __restrict__ W1, const float* __restrict__ b1,
                const float* __restrict__ b2,
                const float* __restrict__ Wr, const float* __restrict__ br,
                const float* __restrict__ b3, const float* __restrict__ b4,
                const float* __restrict__ W5, const float* __restrict__ b5,
                const half4* __restrict__ w1f, const half8* __restrict__ wmlp,
                float* __restrict__ out) {
    __shared__ half4 eaA[2 * 7 * 64];            // A arena (2 x 3.5 KB)
    __shared__ float poolF[1104];                // baseF | xF | rmF (pb/pred alias baseF)
    __shared__ _Float16 xh[G * XST];             // fp16 activation staging

    float* baseF = poolF;                        // [4][128] (dead after edge phase)
    float* xFp   = poolF + 512;                  // [4][132]
    float* rmFp  = poolF + 1040;                 // [4][16]: R(9)+cv(3)+pos(3)
    float* pbF   = poolF;                        // alias
    float* predF = poolF + 384;                  // alias

    const int tid = threadIdx.x;
    const int L   = tid & 63;
    const int wv  = tid >> 6;
    const int lm  = L & 15;
    const int bn0 = blockIdx.x * G;
    const int bB  = bn0 / NN;                    // same graph for all 4 nodes
    const int n0  = bn0 - bB * NN;

    // ---- setup: zero arena (pad rows / pad-k stay zero all launch)
    {
        half4 z = {0, 0, 0, 0};
#pragma unroll
        for (int i = 0; i < 7; ++i) eaA[tid + i * 128] = z;
    }
    if (tid < G) {
        const float* xi = in + (bn0 + tid) * IN;
        float R[9];
        vel_to_R(xi[3], xi[4], xi[5], R);
#pragma unroll
        for (int k = 0; k < 9; ++k) rmFp[tid * 16 + k] = R[k];
        rmFp[tid * 16 + 9]  = R[0] * xi[3] + R[3] * xi[4] + R[6] * xi[5];
        rmFp[tid * 16 + 10] = R[1] * xi[3] + R[4] * xi[4] + R[7] * xi[5];
        rmFp[tid * 16 + 11] = R[2] * xi[3] + R[5] * xi[4] + R[8] * xi[5];
        rmFp[tid * 16 + 12] = xi[0];
        rmFp[tid * 16 + 13] = xi[1];
        rmFp[tid * 16 + 14] = xi[2];
    }
    __syncthreads();

    // folded silu bias: b1 + cv_g . W1[15..17]
    {
        float w15 = W1[15 * H + tid], w16 = W1[16 * H + tid], w17 = W1[17 * H + tid];
        float b1c = b1[tid];
#pragma unroll
        for (int g = 0; g < G; ++g)
            baseF[g * 128 + tid] = b1c + rmFp[g * 16 + 9] * w15
                                 + rmFp[g * 16 + 10] * w16 + rmFp[g * 16 + 11] * w17;
    }
    // W1 B-fragments (this wave's 4 channel-tiles)
    half4 bfr[4];
#pragma unroll
    for (int i = 0; i < 4; ++i) bfr[i] = w1f[(wv * 4 + i) * 64 + L];

    // edge-feature producer for node g -> arena buf (sender data from global)
    auto edge_features = [&](int g, int buf) {
        if (tid < DEG) {
            int nG = n0 + g;
            int s = tid < nG ? tid : tid + 1;     // implicit ~eye edge list
            float Rn[9];
#pragma unroll
            for (int k = 0; k < 9; ++k) Rn[k] = rmFp[g * 16 + k];   // broadcast reads
            float pix = rmFp[g * 16 + 12], piy = rmFp[g * 16 + 13], piz = rmFp[g * 16 + 14];
            const float* xj = in + (bB * NN + s) * IN;
            float rel0 = xj[0] - pix, rel1 = xj[1] - piy, rel2 = xj[2] - piz;
            float vjx = xj[3], vjy = xj[4], vjz = xj[5];
            float Rs[9];
            vel_to_R(vjx, vjy, vjz, Rs);
            float rr0 = Rn[0] * rel0 + Rn[3] * rel1 + Rn[6] * rel2;
            float rr1 = Rn[1] * rel0 + Rn[4] * rel1 + Rn[7] * rel2;
            float rr2 = Rn[2] * rel0 + Rn[5] * rel1 + Rn[8] * rel2;
            float ro00 = Rn[0] * Rs[0] + Rn[3] * Rs[3] + Rn[6] * Rs[6];
            float ro10 = Rn[1] * Rs[0] + Rn[4] * Rs[3] + Rn[7] * Rs[6];
            float ro20 = Rn[2] * Rs[0] + Rn[5] * Rs[3] + Rn[8] * Rs[6];
            float ro21 = Rn[2] * Rs[1] + Rn[5] * Rs[4] + Rn[8] * Rs[7];
            float ro22 = Rn[2] * Rs[2] + Rn[5] * Rs[5] + Rn[8] * Rs[8];
            float dist = sqrtf(rel0 * rel0 + rel1 * rel1 + rel2 * rel2);
            half4 f0, f1, f2;
            f0[0] = (_Float16)rr0; f0[1] = (_Float16)rr1; f0[2] = (_Float16)rr2;
            f0[3] = (_Float16)(fast_atan2(ro10, ro00) * INV_PI);
            f1[0] = (_Float16)(fast_asin(clampf(-ro20, -1.f, 1.f)) * INV_PI);
            f1[1] = (_Float16)(fast_atan2(ro21, ro22) * INV_PI);
            f1[2] = (_Float16)dist;               // |rot_rel| == |rel|
            f1[3] = (_Float16)fast_atan2(rr1, rr0);
            f2[0] = (_Float16)fast_acos(clampf(rr2 * __builtin_amdgcn_rcpf(dist + EPSF), -1.f, 1.f));
            f2[1] = (_Float16)(Rn[0] * vjx + Rn[3] * vjy + Rn[6] * vjz);
            f2[2] = (_Float16)(Rn[1] * vjx + Rn[4] * vjy + Rn[7] * vjz);
            f2[3] = (_Float16)(Rn[2] * vjx + Rn[5] * vjy + Rn[8] * vjz);
            int t = tid >> 4, m = tid & 15;
            half4* dst = eaA + buf * 448 + t * 64;
            dst[m]      = f0;   // k 0..3
            dst[16 + m] = f1;   // k 4..7
            dst[32 + m] = f2;   // k 8..11  (k 12..15 stays zero)
        }
    };

    // ---- pipelined edge phase
    edge_features(0, 0);
    __syncthreads();

#pragma unroll
    for (int g = 0; g < G; ++g) {
        float part[4] = {0.f, 0.f, 0.f, 0.f};
        float bs[4];
        f32x4 c[4];
#pragma unroll
        for (int i = 0; i < 4; ++i) {
            bs[i] = baseF[g * 128 + wv * 64 + i * 16 + lm];
            c[i] = (f32x4){bs[i], bs[i], bs[i], bs[i]};
        }
        const half4* ea = eaA + (g & 1) * 448;
        // uniform 7-tile loop; pad rows contribute silu(bias), cancelled at writer
#pragma unroll
        for (int t = 0; t < 7; ++t) {
            half4 a = ea[t * 64 + L];
            f32x4 d0 = __builtin_amdgcn_mfma_f32_16x16x16f16(a, bfr[0], c[0], 0, 0, 0);
            f32x4 d1 = __builtin_amdgcn_mfma_f32_16x16x16f16(a, bfr[1], c[1], 0, 0, 0);
            f32x4 d2 = __builtin_amdgcn_mfma_f32_16x16x16f16(a, bfr[2], c[2], 0, 0, 0);
            f32x4 d3 = __builtin_amdgcn_mfma_f32_16x16x16f16(a, bfr[3], c[3], 0, 0, 0);
            float dv[16], ev[16];
#pragma unroll
            for (int r = 0; r < 4; ++r) {
                dv[r] = d0[r]; dv[4 + r] = d1[r]; dv[8 + r] = d2[r]; dv[12 + r] = d3[r];
            }
#pragma unroll
            for (int j = 0; j < 16; ++j) ev[j] = __expf(-dv[j]);   // 16 indep trans
#pragma unroll
            for (int j = 0; j < 16; ++j)
                part[j >> 2] += dv[j] * __builtin_amdgcn_rcpf(1.f + ev[j]);
        }
        if (g < G - 1) edge_features(g + 1, (g + 1) & 1);   // overlapped producer
        // reduce over the 4 q-groups; cancel the 13 pad rows: -13*silu(bs)
#pragma unroll
        for (int i = 0; i < 4; ++i) {
            float v = part[i];
            v += __shfl_xor(v, 16, 64);
            v += __shfl_xor(v, 32, 64);
            if (L < 16)
                xFp[g * 132 + wv * 64 + i * 16 + L] = v - 13.f * bs[i] * fast_sig(bs[i]);
        }
        __syncthreads();
    }

    // ---- node MLP: 3 layers, fp16 MFMA (16 MFMA/layer)
    const int q = L >> 4;
#pragma unroll
    for (int layer = 0; layer < 3; ++layer) {
#pragma unroll
        for (int r = 0; r < G; ++r)
            xh[r * XST + tid] = (_Float16)xFp[r * 132 + tid];
        __syncthreads();
        int rowb = (lm & 3) * XST;        // rows 4..15 read dup rows (unread D rows)
        half8 ah[4];
#pragma unroll
        for (int kt = 0; kt < 4; ++kt)
            ah[kt] = *(const half8*)&xh[rowb + kt * 32 + q * 8];
        f32x4 acc[4];
#pragma unroll
        for (int i = 0; i < 4; ++i) acc[i] = (f32x4){0.f, 0.f, 0.f, 0.f};
#pragma unroll
        for (int kt = 0; kt < 4; ++kt) {
            int base = ((layer * 4 + kt) * 8 + wv * 4) * 64 + L;
#pragma unroll
            for (int i = 0; i < 4; ++i) {
                half8 bh = wmlp[base + i * 64];
                acc[i] = __builtin_amdgcn_mfma_f32_16x16x32_f16(ah[kt], bh, acc[i], 0, 0, 0);
            }
        }
        __syncthreads();                  // xh reads done; xF safe to rewrite
        if (L < 16) {                     // quad 0 holds rows 0..3 (the 4 nodes)
#pragma unroll
            for (int i = 0; i < 4; ++i) {
                int ch = wv * 64 + i * 16 + lm;
                if (layer == 0) {
                    float b2c = b2[ch], brc = br[ch];
                    float w3c = Wr[3 * H + ch], w4c = Wr[4 * H + ch], w5c = Wr[5 * H + ch];
#pragma unroll
                    for (int r = 0; r < 4; ++r)
                        xFp[r * 132 + ch] = acc[i][r] * (1.f / 99.f) + b2c
                                          + rmFp[r * 16 + 9] * w3c + rmFp[r * 16 + 10] * w4c
                                          + rmFp[r * 16 + 11] * w5c + brc;
                } else {
                    float bb = (layer == 1) ? b3[ch] : b4[ch];
#pragma unroll
                    for (int r = 0; r < 4; ++r)
                        xFp[r * 132 + ch] = fmaxf(0.f, acc[i][r] + bb);
                }
            }
        }
        __syncthreads();
    }

    // ---- pred = p2 @ W5 + b5, then rotate + residual (pbF/predF alias baseF)
    if (tid < 96) {
        int o = tid >> 4, sl = tid & 15, kb = sl * 8;
        float w5[8];
#pragma unroll
        for (int j = 0; j < 8; ++j) w5[j] = W5[(kb + j) * IN + o];
#pragma unroll
        for (int g = 0; g < G; ++g) {
            float s = 0.f;
#pragma unroll
            for (int j = 0; j < 8; ++j) s = fmaf(xFp[g * 132 + kb + j], w5[j], s);
            pbF[g * 96 + sl * 6 + o] = s;
        }
    }
    __syncthreads();
    if (tid < 24) {
        int g = tid / 6, o = tid - g * 6;
        float s = b5[o];
#pragma unroll
        for (int sl = 0; sl < 16; ++sl) s += pbF[g * 96 + sl * 6 + o];
        predF[g * 8 + o] = s;
    }
    __syncthreads();
    if (tid < 24) {
        int g = tid / 6, o = tid - g * 6;
        int r = (o < 3) ? o : o - 3;
        int off = (o < 3) ? 0 : 3;
        float gl = rmFp[g * 16 + r * 3 + 0] * predF[g * 8 + off + 0]
                 + rmFp[g * 16 + r * 3 + 1] * predF[g * 8 + off + 1]
                 + rmFp[g * 16 + r * 3 + 2] * predF[g * 8 + off + 2];
        int bng = bn0 + g;
        out[bng * IN + o] = in[bng * IN + o] + gl;
    }
}

extern "C" void kernel_launch(void* const* d_in, const int* in_sizes, int n_in,
                              void* d_out, int out_size, void* d_ws, size_t ws_size,
                              hipStream_t stream) {
    const float* in = (const float*)d_in[0];
    const float* W1 = (const float*)d_in[1];
    const float* b1 = (const float*)d_in[2];
    const float* W2 = (const float*)d_in[3];
    const float* b2 = (const float*)d_in[4];
    const float* Wr = (const float*)d_in[5];
    const float* br = (const float*)d_in[6];
    const float* W3 = (const float*)d_in[7];
    const float* b3 = (const float*)d_in[8];
    const float* W4 = (const float*)d_in[9];
    const float* b4 = (const float*)d_in[10];
    const float* W5 = (const float*)d_in[11];
    const float* b5 = (const float*)d_in[12];
    float* out = (float*)d_out;

    half4* w1f  = (half4*)d_ws;                         // 4 KB
    half8* wmlp = (half8*)((char*)d_ws + 4096);         // 96 KB

    const int BN = in_sizes[0] / IN;   // B*N = 12800
    conv_w<<<26, 256, 0, stream>>>(W1, W2, W3, W4, w1f, wmlp);
    locs_fused<<<BN / G, 128, 0, stream>>>(in, W1, b1, b2, Wr, br, b3, b4,
                                           W5, b5, w1f, wmlp, out);
}

// Round 12
// 157.786 us; speedup vs baseline: 1.0343x; 1.0343x over previous
//
#include <hip/hip_runtime.h>
#include <math.h>

#define EPSF 1e-7f
constexpr int NN  = 100;   // nodes per graph
constexpr int DEG = 99;    // fully-connected: deg = NN-1
constexpr int IN  = 6;
constexpr int H   = 128;
constexpr int G   = 4;     // nodes per block
constexpr float INV_PI = 0.3183098861837907f;
constexpr float LOG2E  = 1.4426950408889634f;
constexpr float LN2    = 0.6931471805599453f;

typedef __attribute__((ext_vector_type(4))) _Float16 half4;
typedef __attribute__((ext_vector_type(8))) _Float16 half8;
typedef __attribute__((ext_vector_type(4))) float f32x4;

constexpr int XST = 144;   // fp16 staging stride (288B rows: 16B-aligned)
constexpr int SXS = 15;    // sxr stride in floats: gcd(15,32)=1 -> conflict-free

__device__ __forceinline__ float clampf(float x, float lo, float hi) {
    return fminf(fmaxf(x, lo), hi);
}
// sigmoid in exp2-space: input y = x*log2e, sig = 1/(1+2^-y)
__device__ __forceinline__ float sig2(float y) {
    return __builtin_amdgcn_rcpf(1.f + __builtin_amdgcn_exp2f(-y));
}
// fast atan2: octant-reduced deg-7 minimax (~1e-5 rad; features are fp16)
__device__ __forceinline__ float fast_atan2(float y, float x) {
    float ax = fabsf(x), ay = fabsf(y);
    float mx = fmaxf(ax, ay), mn = fminf(ax, ay);
    float r = mn * __builtin_amdgcn_rcpf(fmaxf(mx, 1e-35f));
    float r2 = r * r;
    float p = fmaf(r2, -0.0851330f, 0.1801410f);
    p = fmaf(r2, p, -0.3302995f);
    p = fmaf(r2, p, 0.9998660f);
    float t = r * p;
    t = (ay > ax) ? (1.5707963267948966f - t) : t;
    t = (x < 0.f) ? (3.14159265358979323f - t) : t;
    return copysignf(t, y);
}
__device__ __forceinline__ float fast_asin(float z) {
    return fast_atan2(z, sqrtf(fmaxf(0.f, (1.f - z) * (1.f + z))));
}
__device__ __forceinline__ float fast_acos(float z) {
    return fast_atan2(sqrtf(fmaxf(0.f, (1.f - z) * (1.f + z))), z);
}
__device__ __forceinline__ void vel_to_R(float vx, float vy, float vz, float* R) {
    float rho = sqrtf(vx * vx + vy * vy + vz * vz);
    float rxy = sqrtf(vx * vx + vy * vy);
    float inv = __builtin_amdgcn_rcpf(rxy);
    bool big = rxy > 1e-30f;
    float ct = big ? vx * inv : 1.f;
    float st = big ? vy * inv : 0.f;
    float cp = clampf(vz * __builtin_amdgcn_rcpf(rho + EPSF), -1.f, 1.f);
    float sp = sqrtf(fmaxf(0.f, 1.f - cp * cp));
    R[0] = cp * ct; R[1] = -st; R[2] = sp * ct;
    R[3] = cp * st; R[4] = ct;  R[5] = sp * st;
    R[6] = -sp;     R[7] = 0.f; R[8] = cp;
}

// ---------------- Kernel A: weights -> fp16 MFMA fragments in ws.
// W1 fragments pre-scaled by log2e (silu runs in exp2 space); W2 fragments
// pre-scaled by ln2 = 1/log2e to undo it after aggregation.
__global__ void conv_w(const float* __restrict__ W1, const float* __restrict__ W2,
                       const float* __restrict__ W3, const float* __restrict__ W4,
                       half4* __restrict__ w1f, half8* __restrict__ wmlp) {
    int t = blockIdx.x * blockDim.x + threadIdx.x;
    if (t >= 104 * 64) return;
    int L = t & 63, f = t >> 6;
    int m = L & 15, qd = L >> 4;
    if (f < 8) {                          // W1 fragments (K=16, k<12 live)
        int n = f * 16 + m;
        half4 v;
#pragma unroll
        for (int j = 0; j < 4; ++j) {
            int k = qd * 4 + j;
            v[j] = (k < 12) ? (_Float16)(W1[k * H + n] * LOG2E) : (_Float16)0.f;
        }
        w1f[f * 64 + L] = v;
    } else {                              // node-MLP weight fragments (K=32)
        int ff = f - 8;
        int layer = ff >> 5, rest = ff & 31;
        int kt = rest >> 3, nt = rest & 7;
        const float* W = (layer == 0) ? W2 : (layer == 1) ? W3 : W4;
        float scale = (layer == 0) ? LN2 : 1.f;
        int n = nt * 16 + m;
        half8 v;
#pragma unroll
        for (int j = 0; j < 8; ++j)
            v[j] = (_Float16)(W[(kt * 32 + qd * 8 + j) * H + n] * scale);
        wmlp[((layer * 4 + kt) * 8 + nt) * 64 + L] = v;
    }
}

// ---------------- Kernel B: fully fused LoCS layer. One block = 4 nodes.
// sxr[100] stride-15 table (gcd(15,32)=1 => <=2-way LDS banks, free): one
// vel_to_R per node per block, producers read sender R/pos/vel from LDS —
// no global loads inside the pipelined region. Silu in exp2 space.
__global__ __launch_bounds__(128)
void locs_fused(const float* __restrict__ in,
                const float* __restrict__ W1, const float* __restrict__ b1,
                const float* __restrict__ b2,
                const float* __restrict__ Wr, const float* __restrict__ br,
                const float* __restrict__ b3, const float* __restrict__ b4,
                const float* __restrict__ W5, const float* __restrict__ b5,
                const half4* __restrict__ w1f, const half8* __restrict__ wmlp,
                float* __restrict__ out) {
    __shared__ half4 eaA[2 * 7 * 64];            // A arena (2 x 3.5 KB)
    __shared__ float sxr[NN * SXS];              // per-node R(9)+pos(3)+vel(3)
    __shared__ float poolF[1056];                // baseF | xF | cvF (pb/pred alias baseF)
    __shared__ _Float16 xh[G * XST];             // fp16 activation staging

    float* baseF = poolF;                        // [4][128] (dead after edge phase)
    float* xFp   = poolF + 512;                  // [4][132]
    float* cvF   = poolF + 1040;                 // [4][4] canon_vel
    float* pbF   = poolF;                        // alias
    float* predF = poolF + 384;                  // alias

    const int tid = threadIdx.x;
    const int L   = tid & 63;
    const int wv  = tid >> 6;
    const int lm  = L & 15;
    const int bn0 = blockIdx.x * G;
    const int bB  = bn0 / NN;                    // same graph for all 4 nodes
    const int n0  = bn0 - bB * NN;

    // ---- setup: zero arena (pad rows / pad-k stay zero all launch)
    {
        half4 z = {0, 0, 0, 0};
#pragma unroll
        for (int i = 0; i < 7; ++i) eaA[tid + i * 128] = z;
    }
    // per-graph-node table (one vel_to_R per node, stride 15 = conflict-free)
    if (tid < NN) {
        const float* xi = in + (bB * NN + tid) * IN;
        float R[9];
        float px = xi[0], py = xi[1], pz = xi[2];
        float vx = xi[3], vy = xi[4], vz = xi[5];
        vel_to_R(vx, vy, vz, R);
        float* dst = sxr + tid * SXS;
#pragma unroll
        for (int k = 0; k < 9; ++k) dst[k] = R[k];
        dst[9] = px; dst[10] = py; dst[11] = pz;
        dst[12] = vx; dst[13] = vy; dst[14] = vz;
    }
    __syncthreads();
    if (tid < G) {                               // canon_vel for the 4 nodes
        const float* rg = sxr + (n0 + tid) * SXS;
        float vx = rg[12], vy = rg[13], vz = rg[14];
        cvF[tid * 4 + 0] = rg[0] * vx + rg[3] * vy + rg[6] * vz;
        cvF[tid * 4 + 1] = rg[1] * vx + rg[4] * vy + rg[7] * vz;
        cvF[tid * 4 + 2] = rg[2] * vx + rg[5] * vy + rg[8] * vz;
    }
    __syncthreads();

    // folded silu bias in exp2 space: (b1 + cv . W1[15..17]) * log2e
    {
        float w15 = W1[15 * H + tid], w16 = W1[16 * H + tid], w17 = W1[17 * H + tid];
        float b1c = b1[tid];
#pragma unroll
        for (int g = 0; g < G; ++g)
            baseF[g * 128 + tid] = (b1c + cvF[g * 4 + 0] * w15
                                  + cvF[g * 4 + 1] * w16 + cvF[g * 4 + 2] * w17) * LOG2E;
    }
    // W1 B-fragments (this wave's 4 channel-tiles)
    half4 bfr[4];
#pragma unroll
    for (int i = 0; i < 4; ++i) bfr[i] = w1f[(wv * 4 + i) * 64 + L];

    // edge-feature producer for node g -> arena buf (all data from sxr)
    auto edge_features = [&](int g, int buf) {
        if (tid < DEG) {
            int nG = n0 + g;
            int s = tid < nG ? tid : tid + 1;     // implicit ~eye edge list
            const float* rn = sxr + nG * SXS;     // broadcast reads (free)
            const float* rs = sxr + s * SXS;      // stride-15: <=2-way (free)
            float Rn[9];
#pragma unroll
            for (int k = 0; k < 9; ++k) Rn[k] = rn[k];
            float rel0 = rs[9] - rn[9], rel1 = rs[10] - rn[10], rel2 = rs[11] - rn[11];
            float vjx = rs[12], vjy = rs[13], vjz = rs[14];
            float Rs0 = rs[0], Rs1 = rs[1], Rs2 = rs[2];
            float Rs3 = rs[3], Rs4 = rs[4], Rs5 = rs[5];
            float Rs6 = rs[6], Rs7 = rs[7], Rs8 = rs[8];
            float rr0 = Rn[0] * rel0 + Rn[3] * rel1 + Rn[6] * rel2;
            float rr1 = Rn[1] * rel0 + Rn[4] * rel1 + Rn[7] * rel2;
            float rr2 = Rn[2] * rel0 + Rn[5] * rel1 + Rn[8] * rel2;
            float ro00 = Rn[0] * Rs0 + Rn[3] * Rs3 + Rn[6] * Rs6;
            float ro10 = Rn[1] * Rs0 + Rn[4] * Rs3 + Rn[7] * Rs6;
            float ro20 = Rn[2] * Rs0 + Rn[5] * Rs3 + Rn[8] * Rs6;
            float ro21 = Rn[2] * Rs1 + Rn[5] * Rs4 + Rn[8] * Rs7;
            float ro22 = Rn[2] * Rs2 + Rn[5] * Rs5 + Rn[8] * Rs8;
            float dist = sqrtf(rel0 * rel0 + rel1 * rel1 + rel2 * rel2);
            half4 f0, f1, f2;
            f0[0] = (_Float16)rr0; f0[1] = (_Float16)rr1; f0[2] = (_Float16)rr2;
            f0[3] = (_Float16)(fast_atan2(ro10, ro00) * INV_PI);
            f1[0] = (_Float16)(fast_asin(clampf(-ro20, -1.f, 1.f)) * INV_PI);
            f1[1] = (_Float16)(fast_atan2(ro21, ro22) * INV_PI);
            f1[2] = (_Float16)dist;               // |rot_rel| == |rel|
            f1[3] = (_Float16)fast_atan2(rr1, rr0);
            f2[0] = (_Float16)fast_acos(clampf(rr2 * __builtin_amdgcn_rcpf(dist + EPSF), -1.f, 1.f));
            f2[1] = (_Float16)(Rn[0] * vjx + Rn[3] * vjy + Rn[6] * vjz);
            f2[2] = (_Float16)(Rn[1] * vjx + Rn[4] * vjy + Rn[7] * vjz);
            f2[3] = (_Float16)(Rn[2] * vjx + Rn[5] * vjy + Rn[8] * vjz);
            int t = tid >> 4, m = tid & 15;
            half4* dst = eaA + buf * 448 + t * 64;
            dst[m]      = f0;   // k 0..3
            dst[16 + m] = f1;   // k 4..7
            dst[32 + m] = f2;   // k 8..11  (k 12..15 stays zero)
        }
    };

    // ---- pipelined edge phase
    edge_features(0, 0);
    __syncthreads();

#pragma unroll
    for (int g = 0; g < G; ++g) {
        float part[4] = {0.f, 0.f, 0.f, 0.f};
        float bs[4];
        f32x4 c[4];
#pragma unroll
        for (int i = 0; i < 4; ++i) {
            bs[i] = baseF[g * 128 + wv * 64 + i * 16 + lm];
            c[i] = (f32x4){bs[i], bs[i], bs[i], bs[i]};
        }
        const half4* ea = eaA + (g & 1) * 448;
        // uniform 7-tile loop in exp2 space: per element 2 VALU + 2 trans
#pragma unroll
        for (int t = 0; t < 7; ++t) {
            half4 a = ea[t * 64 + L];
            f32x4 d0 = __builtin_amdgcn_mfma_f32_16x16x16f16(a, bfr[0], c[0], 0, 0, 0);
            f32x4 d1 = __builtin_amdgcn_mfma_f32_16x16x16f16(a, bfr[1], c[1], 0, 0, 0);
            f32x4 d2 = __builtin_amdgcn_mfma_f32_16x16x16f16(a, bfr[2], c[2], 0, 0, 0);
            f32x4 d3 = __builtin_amdgcn_mfma_f32_16x16x16f16(a, bfr[3], c[3], 0, 0, 0);
#pragma unroll
            for (int r = 0; r < 4; ++r) {
                part[0] += d0[r] * sig2(d0[r]);
                part[1] += d1[r] * sig2(d1[r]);
                part[2] += d2[r] * sig2(d2[r]);
                part[3] += d3[r] * sig2(d3[r]);
            }
        }
        if (g < G - 1) edge_features(g + 1, (g + 1) & 1);   // overlapped producer
        // reduce; cancel 13 pad rows (each contributed bs*sig2(bs)).
        // y-space result; the 1/log2e un-scale is folded into W2 fragments.
#pragma unroll
        for (int i = 0; i < 4; ++i) {
            float v = part[i];
            v += __shfl_xor(v, 16, 64);
            v += __shfl_xor(v, 32, 64);
            if (L < 16)
                xFp[g * 132 + wv * 64 + i * 16 + L] = v - 13.f * bs[i] * sig2(bs[i]);
        }
        __syncthreads();
    }

    // ---- node MLP: 3 layers, fp16 MFMA (16 MFMA/layer)
    const int q = L >> 4;
#pragma unroll
    for (int layer = 0; layer < 3; ++layer) {
#pragma unroll
        for (int r = 0; r < G; ++r)
            xh[r * XST + tid] = (_Float16)xFp[r * 132 + tid];
        __syncthreads();
        int rowb = (lm & 3) * XST;        // rows 4..15 read dup rows (unread D rows)
        half8 ah[4];
#pragma unroll
        for (int kt = 0; kt < 4; ++kt)
            ah[kt] = *(const half8*)&xh[rowb + kt * 32 + q * 8];
        f32x4 acc[4];
#pragma unroll
        for (int i = 0; i < 4; ++i) acc[i] = (f32x4){0.f, 0.f, 0.f, 0.f};
#pragma unroll
        for (int kt = 0; kt < 4; ++kt) {
            int base = ((layer * 4 + kt) * 8 + wv * 4) * 64 + L;
#pragma unroll
            for (int i = 0; i < 4; ++i) {
                half8 bh = wmlp[base + i * 64];
                acc[i] = __builtin_amdgcn_mfma_f32_16x16x32_f16(ah[kt], bh, acc[i], 0, 0, 0);
            }
        }
        __syncthreads();                  // xh reads done; xF safe to rewrite
        if (L < 16) {                     // quad 0 holds rows 0..3 (the 4 nodes)
#pragma unroll
            for (int i = 0; i < 4; ++i) {
                int ch = wv * 64 + i * 16 + lm;
                if (layer == 0) {
                    float b2c = b2[ch], brc = br[ch];
                    float w3c = Wr[3 * H + ch], w4c = Wr[4 * H + ch], w5c = Wr[5 * H + ch];
#pragma unroll
                    for (int r = 0; r < 4; ++r)
                        xFp[r * 132 + ch] = acc[i][r] * (1.f / 99.f) + b2c
                                          + cvF[r * 4 + 0] * w3c + cvF[r * 4 + 1] * w4c
                                          + cvF[r * 4 + 2] * w5c + brc;
                } else {
                    float bb = (layer == 1) ? b3[ch] : b4[ch];
#pragma unroll
                    for (int r = 0; r < 4; ++r)
                        xFp[r * 132 + ch] = fmaxf(0.f, acc[i][r] + bb);
                }
            }
        }
        __syncthreads();
    }

    // ---- pred = p2 @ W5 + b5, then rotate + residual (pbF/predF alias baseF)
    if (tid < 96) {
        int o = tid >> 4, sl = tid & 15, kb = sl * 8;
        float w5[8];
#pragma unroll
        for (int j = 0; j < 8; ++j) w5[j] = W5[(kb + j) * IN + o];
#pragma unroll
        for (int g = 0; g < G; ++g) {
            float s = 0.f;
#pragma unroll
            for (int j = 0; j < 8; ++j) s = fmaf(xFp[g * 132 + kb + j], w5[j], s);
            pbF[g * 96 + sl * 6 + o] = s;
        }
    }
    __syncthreads();
    if (tid < 24) {
        int g = tid / 6, o = tid - g * 6;
        float s = b5[o];
#pragma unroll
        for (int sl = 0; sl < 16; ++sl) s += pbF[g * 96 + sl * 6 + o];
        predF[g * 8 + o] = s;
    }
    __syncthreads();
    if (tid < 24) {
        int g = tid / 6, o = tid - g * 6;
        int r = (o < 3) ? o : o - 3;
        int off = (o < 3) ? 0 : 3;
        const float* Rg = sxr + (n0 + g) * SXS;
        float gl = Rg[r * 3 + 0] * predF[g * 8 + off + 0]
                 + Rg[r * 3 + 1] * predF[g * 8 + off + 1]
                 + Rg[r * 3 + 2] * predF[g * 8 + off + 2];
        int bng = bn0 + g;
        out[bng * IN + o] = Rg[9 + o] + gl;      // in[bng*6+o] == sxr pos/vel
    }
}

extern "C" void kernel_launch(void* const* d_in, const int* in_sizes, int n_in,
                              void* d_out, int out_size, void* d_ws, size_t ws_size,
                              hipStream_t stream) {
    const float* in = (const float*)d_in[0];
    const float* W1 = (const float*)d_in[1];
    const float* b1 = (const float*)d_in[2];
    const float* W2 = (const float*)d_in[3];
    const float* b2 = (const float*)d_in[4];
    const float* Wr = (const float*)d_in[5];
    const float* br = (const float*)d_in[6];
    const float* W3 = (const float*)d_in[7];
    const float* b3 = (const float*)d_in[8];
    const float* W4 = (const float*)d_in[9];
    const float* b4 = (const float*)d_in[10];
    const float* W5 = (const float*)d_in[11];
    const float* b5 = (const float*)d_in[12];
    float* out = (float*)d_out;

    half4* w1f  = (half4*)d_ws;                         // 4 KB
    half8* wmlp = (half8*)((char*)d_ws + 4096);         // 96 KB

    const int BN = in_sizes[0] / IN;   // B*N = 12800
    conv_w<<<26, 256, 0, stream>>>(W1, W2, W3, W4, w1f, wmlp);
    locs_fused<<<BN / G, 128, 0, stream>>>(in, W1, b1, b2, Wr, br, b3, b4,
                                           W5, b5, w1f, wmlp, out);
}

// Round 13
// 144.563 us; speedup vs baseline: 1.1289x; 1.0915x over previous
//
#include <hip/hip_runtime.h>
#include <math.h>

#define EPSF 1e-7f
constexpr int NN  = 100;   // nodes per graph
constexpr int DEG = 99;    // fully-connected: deg = NN-1
constexpr int IN  = 6;
constexpr int H   = 128;
constexpr int G   = 4;     // nodes per block
constexpr float INV_PI = 0.3183098861837907f;
constexpr float LOG2E  = 1.4426950408889634f;
constexpr float LN2    = 0.6931471805599453f;

typedef __attribute__((ext_vector_type(4))) _Float16 half4;
typedef __attribute__((ext_vector_type(8))) _Float16 half8;
typedef __attribute__((ext_vector_type(4))) float f32x4;

constexpr int XST = 144;   // fp16 staging stride (288B rows: 16B-aligned)
constexpr int SXS = 15;    // sxr stride in floats: gcd(15,32)=1 -> conflict-free
constexpr int TS  = 65;    // arena tile stride in half4 (padded: producer-write banks)
constexpr int NT  = 25;    // 25 tiles = 4 nodes x (99 edges + 1 pad) exactly

__device__ __forceinline__ float clampf(float x, float lo, float hi) {
    return fminf(fmaxf(x, lo), hi);
}
// sigmoid in exp2-space: input y = x*log2e, sig = 1/(1+2^-y)
__device__ __forceinline__ float sig2(float y) {
    return __builtin_amdgcn_rcpf(1.f + __builtin_amdgcn_exp2f(-y));
}
// fast atan2: octant-reduced deg-7 minimax (~1e-5 rad; features are fp16)
__device__ __forceinline__ float fast_atan2(float y, float x) {
    float ax = fabsf(x), ay = fabsf(y);
    float mx = fmaxf(ax, ay), mn = fminf(ax, ay);
    float r = mn * __builtin_amdgcn_rcpf(fmaxf(mx, 1e-35f));
    float r2 = r * r;
    float p = fmaf(r2, -0.0851330f, 0.1801410f);
    p = fmaf(r2, p, -0.3302995f);
    p = fmaf(r2, p, 0.9998660f);
    float t = r * p;
    t = (ay > ax) ? (1.5707963267948966f - t) : t;
    t = (x < 0.f) ? (3.14159265358979323f - t) : t;
    return copysignf(t, y);
}
__device__ __forceinline__ float fast_asin(float z) {
    return fast_atan2(z, sqrtf(fmaxf(0.f, (1.f - z) * (1.f + z))));
}
__device__ __forceinline__ float fast_acos(float z) {
    return fast_atan2(sqrtf(fmaxf(0.f, (1.f - z) * (1.f + z))), z);
}
__device__ __forceinline__ void vel_to_R(float vx, float vy, float vz, float* R) {
    float rho = sqrtf(vx * vx + vy * vy + vz * vz);
    float rxy = sqrtf(vx * vx + vy * vy);
    float inv = __builtin_amdgcn_rcpf(rxy);
    bool big = rxy > 1e-30f;
    float ct = big ? vx * inv : 1.f;
    float st = big ? vy * inv : 0.f;
    float cp = clampf(vz * __builtin_amdgcn_rcpf(rho + EPSF), -1.f, 1.f);
    float sp = sqrtf(fmaxf(0.f, 1.f - cp * cp));
    R[0] = cp * ct; R[1] = -st; R[2] = sp * ct;
    R[3] = cp * st; R[4] = ct;  R[5] = sp * st;
    R[6] = -sp;     R[7] = 0.f; R[8] = cp;
}

// ---------------- Kernel A: weights -> fp16 MFMA fragments in ws.
// W1 pre-scaled by log2e (silu in exp2 space); W2 pre-scaled by ln2 to undo.
__global__ void conv_w(const float* __restrict__ W1, const float* __restrict__ W2,
                       const float* __restrict__ W3, const float* __restrict__ W4,
                       half4* __restrict__ w1f, half8* __restrict__ wmlp) {
    int t = blockIdx.x * blockDim.x + threadIdx.x;
    if (t >= 104 * 64) return;
    int L = t & 63, f = t >> 6;
    int m = L & 15, qd = L >> 4;
    if (f < 8) {                          // W1 fragments (K=16, k<12 live)
        int n = f * 16 + m;
        half4 v;
#pragma unroll
        for (int j = 0; j < 4; ++j) {
            int k = qd * 4 + j;
            v[j] = (k < 12) ? (_Float16)(W1[k * H + n] * LOG2E) : (_Float16)0.f;
        }
        w1f[f * 64 + L] = v;
    } else {                              // node-MLP weight fragments (K=32)
        int ff = f - 8;
        int layer = ff >> 5, rest = ff & 31;
        int kt = rest >> 3, nt = rest & 7;
        const float* W = (layer == 0) ? W2 : (layer == 1) ? W3 : W4;
        float scale = (layer == 0) ? LN2 : 1.f;
        int n = nt * 16 + m;
        half8 v;
#pragma unroll
        for (int j = 0; j < 8; ++j)
            v[j] = (_Float16)(W[(kt * 32 + qd * 8 + j) * H + n] * scale);
        wmlp[((layer * 4 + kt) * 8 + nt) * 64 + L] = v;
    }
}

// ---------------- Kernel B: fully fused LoCS layer. One block = 4 nodes.
// PERFECT-PACKED edge arena: quad q of every MFMA tile belongs to node q
// (A-row q*4+r = node q, edge 4t+r), so 4x99 edges + 4 pads = exactly 25
// tiles. Each lane accumulates only its own node => no shfl reduction; the
// single pad (t=24,r=3) is cancelled uniformly via -bs*sig2(bs).
__global__ __launch_bounds__(128)
void locs_fused(const float* __restrict__ in,
                const float* __restrict__ W1, const float* __restrict__ b1,
                const float* __restrict__ b2,
                const float* __restrict__ Wr, const float* __restrict__ br,
                const float* __restrict__ b3, const float* __restrict__ b4,
                const float* __restrict__ W5, const float* __restrict__ b5,
                const half4* __restrict__ w1f, const half8* __restrict__ wmlp,
                float* __restrict__ out) {
    __shared__ half4 eaA[NT * TS];               // packed A arena (13 KB)
    __shared__ float sxr[NN * SXS];              // per-node R(9)+pos(3)+vel(3)
    __shared__ float poolF[1056];                // baseF | xF | cvF (pb/pred alias baseF)
    __shared__ _Float16 xh[G * XST];             // fp16 activation staging

    float* baseF = poolF;                        // [4][128] (dead after edge phase)
    float* xFp   = poolF + 512;                  // [4][132]
    float* cvF   = poolF + 1040;                 // [4][4] canon_vel
    float* pbF   = poolF;                        // alias
    float* predF = poolF + 384;                  // alias

    const int tid = threadIdx.x;
    const int L   = tid & 63;
    const int wv  = tid >> 6;
    const int q   = L >> 4;                      // lane quad == owned node
    const int lm  = L & 15;
    const int bn0 = blockIdx.x * G;
    const int bB  = bn0 / NN;                    // same graph for all 4 nodes
    const int n0  = bn0 - bB * NN;

    // ---- setup: zero arena (pad rows / pad-k stay zero all launch)
    for (int i = tid; i < NT * TS; i += 128) eaA[i] = (half4){0, 0, 0, 0};
    // per-graph-node table (one vel_to_R per node, stride 15 = conflict-free)
    if (tid < NN) {
        const float* xi = in + (bB * NN + tid) * IN;
        float R[9];
        float px = xi[0], py = xi[1], pz = xi[2];
        float vx = xi[3], vy = xi[4], vz = xi[5];
        vel_to_R(vx, vy, vz, R);
        float* dst = sxr + tid * SXS;
#pragma unroll
        for (int k = 0; k < 9; ++k) dst[k] = R[k];
        dst[9] = px; dst[10] = py; dst[11] = pz;
        dst[12] = vx; dst[13] = vy; dst[14] = vz;
    }
    __syncthreads();
    if (tid < G) {                               // canon_vel for the 4 nodes
        const float* rg = sxr + (n0 + tid) * SXS;
        float vx = rg[12], vy = rg[13], vz = rg[14];
        cvF[tid * 4 + 0] = rg[0] * vx + rg[3] * vy + rg[6] * vz;
        cvF[tid * 4 + 1] = rg[1] * vx + rg[4] * vy + rg[7] * vz;
        cvF[tid * 4 + 2] = rg[2] * vx + rg[5] * vy + rg[8] * vz;
    }
    __syncthreads();

    // folded silu bias in exp2 space: (b1 + cv . W1[15..17]) * log2e
    {
        float w15 = W1[15 * H + tid], w16 = W1[16 * H + tid], w17 = W1[17 * H + tid];
        float b1c = b1[tid];
#pragma unroll
        for (int g = 0; g < G; ++g)
            baseF[g * 128 + tid] = (b1c + cvF[g * 4 + 0] * w15
                                  + cvF[g * 4 + 1] * w16 + cvF[g * 4 + 2] * w17) * LOG2E;
    }
    // W1 B-fragments (this wave's 4 channel-tiles)
    half4 bfr[4];
#pragma unroll
    for (int i = 0; i < 4; ++i) bfr[i] = w1f[(wv * 4 + i) * 64 + L];

    // ---- dense producer: all 4 nodes' edge features, packed layout
#pragma unroll
    for (int rnd = 0; rnd < 4; ++rnd) {
        int j = tid + rnd * 128;
        if (j < G * DEG) {
            int g = j / DEG;                     // owning node 0..3
            int e = j - g * DEG;                 // edge index 0..98
            int nG = n0 + g;
            int s = e < nG ? e : e + 1;          // implicit ~eye edge list
            const float* rn = sxr + nG * SXS;    // broadcast-ish reads
            const float* rs = sxr + s * SXS;     // stride-15: conflict-free
            float Rn[9];
#pragma unroll
            for (int k = 0; k < 9; ++k) Rn[k] = rn[k];
            float rel0 = rs[9] - rn[9], rel1 = rs[10] - rn[10], rel2 = rs[11] - rn[11];
            float vjx = rs[12], vjy = rs[13], vjz = rs[14];
            float Rs0 = rs[0], Rs1 = rs[1], Rs2 = rs[2];
            float Rs3 = rs[3], Rs4 = rs[4], Rs5 = rs[5];
            float Rs6 = rs[6], Rs7 = rs[7], Rs8 = rs[8];
            float rr0 = Rn[0] * rel0 + Rn[3] * rel1 + Rn[6] * rel2;
            float rr1 = Rn[1] * rel0 + Rn[4] * rel1 + Rn[7] * rel2;
            float rr2 = Rn[2] * rel0 + Rn[5] * rel1 + Rn[8] * rel2;
            float ro00 = Rn[0] * Rs0 + Rn[3] * Rs3 + Rn[6] * Rs6;
            float ro10 = Rn[1] * Rs0 + Rn[4] * Rs3 + Rn[7] * Rs6;
            float ro20 = Rn[2] * Rs0 + Rn[5] * Rs3 + Rn[8] * Rs6;
            float ro21 = Rn[2] * Rs1 + Rn[5] * Rs4 + Rn[8] * Rs7;
            float ro22 = Rn[2] * Rs2 + Rn[5] * Rs5 + Rn[8] * Rs8;
            float dist = sqrtf(rel0 * rel0 + rel1 * rel1 + rel2 * rel2);
            half4 f0, f1, f2;
            f0[0] = (_Float16)rr0; f0[1] = (_Float16)rr1; f0[2] = (_Float16)rr2;
            f0[3] = (_Float16)(fast_atan2(ro10, ro00) * INV_PI);
            f1[0] = (_Float16)(fast_asin(clampf(-ro20, -1.f, 1.f)) * INV_PI);
            f1[1] = (_Float16)(fast_atan2(ro21, ro22) * INV_PI);
            f1[2] = (_Float16)dist;              // |rot_rel| == |rel|
            f1[3] = (_Float16)fast_atan2(rr1, rr0);
            f2[0] = (_Float16)fast_acos(clampf(rr2 * __builtin_amdgcn_rcpf(dist + EPSF), -1.f, 1.f));
            f2[1] = (_Float16)(Rn[0] * vjx + Rn[3] * vjy + Rn[6] * vjz);
            f2[2] = (_Float16)(Rn[1] * vjx + Rn[4] * vjy + Rn[7] * vjz);
            f2[3] = (_Float16)(Rn[2] * vjx + Rn[5] * vjy + Rn[8] * vjz);
            int t = e >> 2;                      // tile
            int mrow = g * 4 + (e & 3);          // A row: node quad + edge%4
            half4* dst = eaA + t * TS + mrow;
            dst[0]  = f0;   // k 0..3
            dst[16] = f1;   // k 4..7
            dst[32] = f2;   // k 8..11 (k 12..15 stays zero)
        }
    }
    __syncthreads();

    // ---- consumer: one uniform 25-tile MFMA + silu stream (lane owns node q)
    {
        float bs[4], part[4] = {0.f, 0.f, 0.f, 0.f};
        f32x4 c[4];
#pragma unroll
        for (int i = 0; i < 4; ++i) {
            bs[i] = baseF[q * 128 + wv * 64 + i * 16 + lm];
            c[i] = (f32x4){bs[i], bs[i], bs[i], bs[i]};
        }
#pragma unroll
        for (int t = 0; t < NT; ++t) {
            half4 a = eaA[t * TS + L];
            f32x4 d0 = __builtin_amdgcn_mfma_f32_16x16x16f16(a, bfr[0], c[0], 0, 0, 0);
            f32x4 d1 = __builtin_amdgcn_mfma_f32_16x16x16f16(a, bfr[1], c[1], 0, 0, 0);
            f32x4 d2 = __builtin_amdgcn_mfma_f32_16x16x16f16(a, bfr[2], c[2], 0, 0, 0);
            f32x4 d3 = __builtin_amdgcn_mfma_f32_16x16x16f16(a, bfr[3], c[3], 0, 0, 0);
#pragma unroll
            for (int r = 0; r < 4; ++r) {
                part[0] += d0[r] * sig2(d0[r]);
                part[1] += d1[r] * sig2(d1[r]);
                part[2] += d2[r] * sig2(d2[r]);
                part[3] += d3[r] * sig2(d3[r]);
            }
        }
        // exactly one pad element per node (t=24, r=3): cancel uniformly
#pragma unroll
        for (int i = 0; i < 4; ++i) {
            float v = part[i] - bs[i] * sig2(bs[i]);
            xFp[q * 132 + wv * 64 + i * 16 + lm] = v;   // lane's own node q
        }
    }
    __syncthreads();

    // ---- node MLP: 3 layers, fp16 MFMA (16 MFMA/layer)
#pragma unroll
    for (int layer = 0; layer < 3; ++layer) {
#pragma unroll
        for (int r = 0; r < G; ++r)
            xh[r * XST + tid] = (_Float16)xFp[r * 132 + tid];
        __syncthreads();
        int rowb = (lm & 3) * XST;        // rows 4..15 read dup rows (unread D rows)
        half8 ah[4];
#pragma unroll
        for (int kt = 0; kt < 4; ++kt)
            ah[kt] = *(const half8*)&xh[rowb + kt * 32 + q * 8];
        f32x4 acc[4];
#pragma unroll
        for (int i = 0; i < 4; ++i) acc[i] = (f32x4){0.f, 0.f, 0.f, 0.f};
#pragma unroll
        for (int kt = 0; kt < 4; ++kt) {
            int base = ((layer * 4 + kt) * 8 + wv * 4) * 64 + L;
#pragma unroll
            for (int i = 0; i < 4; ++i) {
                half8 bh = wmlp[base + i * 64];
                acc[i] = __builtin_amdgcn_mfma_f32_16x16x32_f16(ah[kt], bh, acc[i], 0, 0, 0);
            }
        }
        __syncthreads();                  // xh reads done; xF safe to rewrite
        if (L < 16) {                     // quad 0 holds rows 0..3 (the 4 nodes)
#pragma unroll
            for (int i = 0; i < 4; ++i) {
                int ch = wv * 64 + i * 16 + lm;
                if (layer == 0) {
                    float b2c = b2[ch], brc = br[ch];
                    float w3c = Wr[3 * H + ch], w4c = Wr[4 * H + ch], w5c = Wr[5 * H + ch];
#pragma unroll
                    for (int r = 0; r < 4; ++r)
                        xFp[r * 132 + ch] = acc[i][r] * (1.f / 99.f) + b2c
                                          + cvF[r * 4 + 0] * w3c + cvF[r * 4 + 1] * w4c
                                          + cvF[r * 4 + 2] * w5c + brc;
                } else {
                    float bb = (layer == 1) ? b3[ch] : b4[ch];
#pragma unroll
                    for (int r = 0; r < 4; ++r)
                        xFp[r * 132 + ch] = fmaxf(0.f, acc[i][r] + bb);
                }
            }
        }
        __syncthreads();
    }

    // ---- pred = p2 @ W5 + b5, then rotate + residual (pbF/predF alias baseF)
    if (tid < 96) {
        int o = tid >> 4, sl = tid & 15, kb = sl * 8;
        float w5[8];
#pragma unroll
        for (int j = 0; j < 8; ++j) w5[j] = W5[(kb + j) * IN + o];
#pragma unroll
        for (int g = 0; g < G; ++g) {
            float s = 0.f;
#pragma unroll
            for (int j = 0; j < 8; ++j) s = fmaf(xFp[g * 132 + kb + j], w5[j], s);
            pbF[g * 96 + sl * 6 + o] = s;
        }
    }
    __syncthreads();
    if (tid < 24) {
        int g = tid / 6, o = tid - g * 6;
        float s = b5[o];
#pragma unroll
        for (int sl = 0; sl < 16; ++sl) s += pbF[g * 96 + sl * 6 + o];
        predF[g * 8 + o] = s;
    }
    __syncthreads();
    if (tid < 24) {
        int g = tid / 6, o = tid - g * 6;
        int r = (o < 3) ? o : o - 3;
        int off = (o < 3) ? 0 : 3;
        const float* Rg = sxr + (n0 + g) * SXS;
        float gl = Rg[r * 3 + 0] * predF[g * 8 + off + 0]
                 + Rg[r * 3 + 1] * predF[g * 8 + off + 1]
                 + Rg[r * 3 + 2] * predF[g * 8 + off + 2];
        int bng = bn0 + g;
        out[bng * IN + o] = Rg[9 + o] + gl;      // in[bng*6+o] == sxr pos/vel
    }
}

extern "C" void kernel_launch(void* const* d_in, const int* in_sizes, int n_in,
                              void* d_out, int out_size, void* d_ws, size_t ws_size,
                              hipStream_t stream) {
    const float* in = (const float*)d_in[0];
    const float* W1 = (const float*)d_in[1];
    const float* b1 = (const float*)d_in[2];
    const float* W2 = (const float*)d_in[3];
    const float* b2 = (const float*)d_in[4];
    const float* Wr = (const float*)d_in[5];
    const float* br = (const float*)d_in[6];
    const float* W3 = (const float*)d_in[7];
    const float* b3 = (const float*)d_in[8];
    const float* W4 = (const float*)d_in[9];
    const float* b4 = (const float*)d_in[10];
    const float* W5 = (const float*)d_in[11];
    const float* b5 = (const float*)d_in[12];
    float* out = (float*)d_out;

    half4* w1f  = (half4*)d_ws;                         // 4 KB
    half8* wmlp = (half8*)((char*)d_ws + 4096);         // 96 KB

    const int BN = in_sizes[0] / IN;   // B*N = 12800
    conv_w<<<26, 256, 0, stream>>>(W1, W2, W3, W4, w1f, wmlp);
    locs_fused<<<BN / G, 128, 0, stream>>>(in, W1, b1, b2, Wr, br, b3, b4,
                                           W5, b5, w1f, wmlp, out);
}

// Round 14
// 142.781 us; speedup vs baseline: 1.1429x; 1.0125x over previous
//
#include <hip/hip_runtime.h>
#include <math.h>

#define EPSF 1e-7f
constexpr int NN  = 100;   // nodes per graph
constexpr int DEG = 99;    // fully-connected: deg = NN-1
constexpr int IN  = 6;
constexpr int H   = 128;
constexpr int G   = 4;     // nodes per block
constexpr float INV_PI = 0.3183098861837907f;
constexpr float LOG2E  = 1.4426950408889634f;
constexpr float LN2    = 0.6931471805599453f;

typedef __attribute__((ext_vector_type(4))) _Float16 half4;
typedef __attribute__((ext_vector_type(8))) _Float16 half8;
typedef __attribute__((ext_vector_type(4))) float f32x4;

constexpr int XST = 144;   // fp16 staging stride (288B rows: 16B-aligned)
constexpr int SXS = 15;    // sxr stride in floats: gcd(15,32)=1 -> conflict-free
constexpr int TS  = 50;    // compact tile stride in half4: 48 live + zero slot @48
constexpr int NT  = 25;    // 25 tiles = 4 nodes x (99 edges + 1 pad) exactly

__device__ __forceinline__ float clampf(float x, float lo, float hi) {
    return fminf(fmaxf(x, lo), hi);
}
// sigmoid in exp2-space: input y = x*log2e, sig = 1/(1+2^-y)
__device__ __forceinline__ float sig2(float y) {
    return __builtin_amdgcn_rcpf(1.f + __builtin_amdgcn_exp2f(-y));
}
// fast atan2: octant-reduced deg-7 minimax (~1e-5 rad; features are fp16)
__device__ __forceinline__ float fast_atan2(float y, float x) {
    float ax = fabsf(x), ay = fabsf(y);
    float mx = fmaxf(ax, ay), mn = fminf(ax, ay);
    float r = mn * __builtin_amdgcn_rcpf(fmaxf(mx, 1e-35f));
    float r2 = r * r;
    float p = fmaf(r2, -0.0851330f, 0.1801410f);
    p = fmaf(r2, p, -0.3302995f);
    p = fmaf(r2, p, 0.9998660f);
    float t = r * p;
    t = (ay > ax) ? (1.5707963267948966f - t) : t;
    t = (x < 0.f) ? (3.14159265358979323f - t) : t;
    return copysignf(t, y);
}
__device__ __forceinline__ float fast_asin(float z) {
    return fast_atan2(z, sqrtf(fmaxf(0.f, (1.f - z) * (1.f + z))));
}
__device__ __forceinline__ float fast_acos(float z) {
    return fast_atan2(sqrtf(fmaxf(0.f, (1.f - z) * (1.f + z))), z);
}
__device__ __forceinline__ void vel_to_R(float vx, float vy, float vz, float* R) {
    float rho = sqrtf(vx * vx + vy * vy + vz * vz);
    float rxy = sqrtf(vx * vx + vy * vy);
    float inv = __builtin_amdgcn_rcpf(rxy);
    bool big = rxy > 1e-30f;
    float ct = big ? vx * inv : 1.f;
    float st = big ? vy * inv : 0.f;
    float cp = clampf(vz * __builtin_amdgcn_rcpf(rho + EPSF), -1.f, 1.f);
    float sp = sqrtf(fmaxf(0.f, 1.f - cp * cp));
    R[0] = cp * ct; R[1] = -st; R[2] = sp * ct;
    R[3] = cp * st; R[4] = ct;  R[5] = sp * st;
    R[6] = -sp;     R[7] = 0.f; R[8] = cp;
}

// ---------------- Kernel A: weights -> fp16 MFMA fragments in ws.
// W1 pre-scaled by log2e (silu in exp2 space); W2 pre-scaled by ln2 to undo.
__global__ void conv_w(const float* __restrict__ W1, const float* __restrict__ W2,
                       const float* __restrict__ W3, const float* __restrict__ W4,
                       half4* __restrict__ w1f, half8* __restrict__ wmlp) {
    int t = blockIdx.x * blockDim.x + threadIdx.x;
    if (t >= 104 * 64) return;
    int L = t & 63, f = t >> 6;
    int m = L & 15, qd = L >> 4;
    if (f < 8) {                          // W1 fragments (K=16, k<12 live)
        int n = f * 16 + m;
        half4 v;
#pragma unroll
        for (int j = 0; j < 4; ++j) {
            int k = qd * 4 + j;
            v[j] = (k < 12) ? (_Float16)(W1[k * H + n] * LOG2E) : (_Float16)0.f;
        }
        w1f[f * 64 + L] = v;
    } else {                              // node-MLP weight fragments (K=32)
        int ff = f - 8;
        int layer = ff >> 5, rest = ff & 31;
        int kt = rest >> 3, nt = rest & 7;
        const float* W = (layer == 0) ? W2 : (layer == 1) ? W3 : W4;
        float scale = (layer == 0) ? LN2 : 1.f;
        int n = nt * 16 + m;
        half8 v;
#pragma unroll
        for (int j = 0; j < 8; ++j)
            v[j] = (_Float16)(W[(kt * 32 + qd * 8 + j) * H + n] * scale);
        wmlp[((layer * 4 + kt) * 8 + nt) * 64 + L] = v;
    }
}

// ---------------- Kernel B: fully fused LoCS layer. One block = 4 nodes.
// LDS diet (24.5 -> 19.8 KB => 8 blocks/CU): compact arena stores only the 12
// live k-slots per tile (+1 zero slot; qd==3 lanes redirect there), silu bias
// computed in-register (baseF deleted), fp16 staging aliases the dead arena.
__global__ __launch_bounds__(128)
void locs_fused(const float* __restrict__ in,
                const float* __restrict__ W1, const float* __restrict__ b1,
                const float* __restrict__ b2,
                const float* __restrict__ Wr, const float* __restrict__ br,
                const float* __restrict__ b3, const float* __restrict__ b4,
                const float* __restrict__ W5, const float* __restrict__ b5,
                const half4* __restrict__ w1f, const half8* __restrict__ wmlp,
                float* __restrict__ out) {
    __shared__ _Float16 hpool[NT * TS * 4];      // arena (10 KB); reused as xh staging
    __shared__ float sxr[NN * SXS];              // per-node R(9)+pos(3)+vel(3)
    __shared__ float xFp[G * 132];               // fp32 activations (padded stride)
    __shared__ float cvF[16];                    // canon_vel per node
    __shared__ float pbF[G * 96];                // W5 partials
    __shared__ float predF[G * 8];

    const int tid = threadIdx.x;
    const int L   = tid & 63;
    const int wv  = tid >> 6;
    const int q   = L >> 4;                      // lane quad == owned node / kslot
    const int lm  = L & 15;
    const int bn0 = blockIdx.x * G;
    const int bB  = bn0 / NN;                    // same graph for all 4 nodes
    const int n0  = bn0 - bB * NN;

    // ---- setup: zero arena (pad rows / zero slots stay zero all launch)
    {
        half4 z = {0, 0, 0, 0};
        for (int i = tid; i < NT * TS; i += 128) *(half4*)&hpool[i * 4] = z;
    }
    // per-graph-node table (one vel_to_R per node, stride 15 = conflict-free)
    if (tid < NN) {
        const float* xi = in + (bB * NN + tid) * IN;
        float R[9];
        float px = xi[0], py = xi[1], pz = xi[2];
        float vx = xi[3], vy = xi[4], vz = xi[5];
        vel_to_R(vx, vy, vz, R);
        float* dst = sxr + tid * SXS;
#pragma unroll
        for (int k = 0; k < 9; ++k) dst[k] = R[k];
        dst[9] = px; dst[10] = py; dst[11] = pz;
        dst[12] = vx; dst[13] = vy; dst[14] = vz;
    }
    __syncthreads();
    if (tid < G) {                               // canon_vel for the 4 nodes
        const float* rg = sxr + (n0 + tid) * SXS;
        float vx = rg[12], vy = rg[13], vz = rg[14];
        cvF[tid * 4 + 0] = rg[0] * vx + rg[3] * vy + rg[6] * vz;
        cvF[tid * 4 + 1] = rg[1] * vx + rg[4] * vy + rg[7] * vz;
        cvF[tid * 4 + 2] = rg[2] * vx + rg[5] * vy + rg[8] * vz;
    }
    // W1 B-fragments (this wave's 4 channel-tiles)
    half4 bfr[4];
#pragma unroll
    for (int i = 0; i < 4; ++i) bfr[i] = w1f[(wv * 4 + i) * 64 + L];

    // ---- dense producer: all 4 nodes' edge features, packed compact layout
#pragma unroll
    for (int rnd = 0; rnd < 4; ++rnd) {
        int j = tid + rnd * 128;
        if (j < G * DEG) {
            int g = j / DEG;                     // owning node 0..3
            int e = j - g * DEG;                 // edge index 0..98
            int nG = n0 + g;
            int s = e < nG ? e : e + 1;          // implicit ~eye edge list
            const float* rn = sxr + nG * SXS;
            const float* rs = sxr + s * SXS;     // stride-15: conflict-free
            float Rn[9];
#pragma unroll
            for (int k = 0; k < 9; ++k) Rn[k] = rn[k];
            float rel0 = rs[9] - rn[9], rel1 = rs[10] - rn[10], rel2 = rs[11] - rn[11];
            float vjx = rs[12], vjy = rs[13], vjz = rs[14];
            float Rs0 = rs[0], Rs1 = rs[1], Rs2 = rs[2];
            float Rs3 = rs[3], Rs4 = rs[4], Rs5 = rs[5];
            float Rs6 = rs[6], Rs7 = rs[7], Rs8 = rs[8];
            float rr0 = Rn[0] * rel0 + Rn[3] * rel1 + Rn[6] * rel2;
            float rr1 = Rn[1] * rel0 + Rn[4] * rel1 + Rn[7] * rel2;
            float rr2 = Rn[2] * rel0 + Rn[5] * rel1 + Rn[8] * rel2;
            float ro00 = Rn[0] * Rs0 + Rn[3] * Rs3 + Rn[6] * Rs6;
            float ro10 = Rn[1] * Rs0 + Rn[4] * Rs3 + Rn[7] * Rs6;
            float ro20 = Rn[2] * Rs0 + Rn[5] * Rs3 + Rn[8] * Rs6;
            float ro21 = Rn[2] * Rs1 + Rn[5] * Rs4 + Rn[8] * Rs7;
            float ro22 = Rn[2] * Rs2 + Rn[5] * Rs5 + Rn[8] * Rs8;
            float dist = sqrtf(rel0 * rel0 + rel1 * rel1 + rel2 * rel2);
            half4 f0, f1, f2;
            f0[0] = (_Float16)rr0; f0[1] = (_Float16)rr1; f0[2] = (_Float16)rr2;
            f0[3] = (_Float16)(fast_atan2(ro10, ro00) * INV_PI);
            f1[0] = (_Float16)(fast_asin(clampf(-ro20, -1.f, 1.f)) * INV_PI);
            f1[1] = (_Float16)(fast_atan2(ro21, ro22) * INV_PI);
            f1[2] = (_Float16)dist;              // |rot_rel| == |rel|
            f1[3] = (_Float16)fast_atan2(rr1, rr0);
            f2[0] = (_Float16)fast_acos(clampf(rr2 * __builtin_amdgcn_rcpf(dist + EPSF), -1.f, 1.f));
            f2[1] = (_Float16)(Rn[0] * vjx + Rn[3] * vjy + Rn[6] * vjz);
            f2[2] = (_Float16)(Rn[1] * vjx + Rn[4] * vjy + Rn[7] * vjz);
            f2[3] = (_Float16)(Rn[2] * vjx + Rn[5] * vjy + Rn[8] * vjz);
            int t = e >> 2;                      // tile
            int mrow = g * 4 + (e & 3);          // A row: node quad + edge%4
            _Float16* dst = hpool + (t * TS + mrow) * 4;
            *(half4*)(dst +   0)      = f0;      // kslot 0
            *(half4*)(dst + 16 * 4)   = f1;      // kslot 1
            *(half4*)(dst + 32 * 4)   = f2;      // kslot 2 (kslot 3 = zeros)
        }
    }

    // in-register folded silu bias (exp2 space) for lane's own node q
    float bs[4];
    {
        float cv0 = cvF[q * 4 + 0], cv1 = cvF[q * 4 + 1], cv2 = cvF[q * 4 + 2];
#pragma unroll
        for (int i = 0; i < 4; ++i) {
            int ch = wv * 64 + i * 16 + lm;
            bs[i] = (b1[ch] + cv0 * W1[15 * H + ch] + cv1 * W1[16 * H + ch]
                   + cv2 * W1[17 * H + ch]) * LOG2E;
        }
    }
    __syncthreads();

    // ---- consumer: one uniform 25-tile MFMA + silu stream (lane owns node q)
    {
        float part[4] = {0.f, 0.f, 0.f, 0.f};
        f32x4 c[4];
#pragma unroll
        for (int i = 0; i < 4; ++i) c[i] = (f32x4){bs[i], bs[i], bs[i], bs[i]};
        const int loff = (q < 3) ? (q * 16 + lm) : 48;   // qd==3 -> zero slot
#pragma unroll
        for (int t = 0; t < NT; ++t) {
            half4 a = *(const half4*)&hpool[(t * TS + loff) * 4];
            f32x4 d0 = __builtin_amdgcn_mfma_f32_16x16x16f16(a, bfr[0], c[0], 0, 0, 0);
            f32x4 d1 = __builtin_amdgcn_mfma_f32_16x16x16f16(a, bfr[1], c[1], 0, 0, 0);
            f32x4 d2 = __builtin_amdgcn_mfma_f32_16x16x16f16(a, bfr[2], c[2], 0, 0, 0);
            f32x4 d3 = __builtin_amdgcn_mfma_f32_16x16x16f16(a, bfr[3], c[3], 0, 0, 0);
#pragma unroll
            for (int r = 0; r < 4; ++r) {
                part[0] += d0[r] * sig2(d0[r]);
                part[1] += d1[r] * sig2(d1[r]);
                part[2] += d2[r] * sig2(d2[r]);
                part[3] += d3[r] * sig2(d3[r]);
            }
        }
        // exactly one pad element per node (t=24, r=3): cancel uniformly
#pragma unroll
        for (int i = 0; i < 4; ++i)
            xFp[q * 132 + wv * 64 + i * 16 + lm] = part[i] - bs[i] * sig2(bs[i]);
    }
    __syncthreads();

    // ---- node MLP: 3 layers, fp16 MFMA; staging aliases the dead arena
    _Float16* xh = hpool;
#pragma unroll
    for (int layer = 0; layer < 3; ++layer) {
#pragma unroll
        for (int r = 0; r < G; ++r)
            xh[r * XST + tid] = (_Float16)xFp[r * 132 + tid];
        __syncthreads();
        int rowb = (lm & 3) * XST;        // rows 4..15 read dup rows (unread D rows)
        half8 ah[4];
#pragma unroll
        for (int kt = 0; kt < 4; ++kt)
            ah[kt] = *(const half8*)&xh[rowb + kt * 32 + q * 8];
        f32x4 acc[4];
#pragma unroll
        for (int i = 0; i < 4; ++i) acc[i] = (f32x4){0.f, 0.f, 0.f, 0.f};
#pragma unroll
        for (int kt = 0; kt < 4; ++kt) {
            int base = ((layer * 4 + kt) * 8 + wv * 4) * 64 + L;
#pragma unroll
            for (int i = 0; i < 4; ++i) {
                half8 bh = wmlp[base + i * 64];
                acc[i] = __builtin_amdgcn_mfma_f32_16x16x32_f16(ah[kt], bh, acc[i], 0, 0, 0);
            }
        }
        __syncthreads();                  // xh reads done; xFp safe to rewrite
        if (L < 16) {                     // quad 0 holds rows 0..3 (the 4 nodes)
#pragma unroll
            for (int i = 0; i < 4; ++i) {
                int ch = wv * 64 + i * 16 + lm;
                if (layer == 0) {
                    float b2c = b2[ch], brc = br[ch];
                    float w3c = Wr[3 * H + ch], w4c = Wr[4 * H + ch], w5c = Wr[5 * H + ch];
#pragma unroll
                    for (int r = 0; r < 4; ++r)
                        xFp[r * 132 + ch] = acc[i][r] * (1.f / 99.f) + b2c
                                          + cvF[r * 4 + 0] * w3c + cvF[r * 4 + 1] * w4c
                                          + cvF[r * 4 + 2] * w5c + brc;
                } else {
                    float bb = (layer == 1) ? b3[ch] : b4[ch];
#pragma unroll
                    for (int r = 0; r < 4; ++r)
                        xFp[r * 132 + ch] = fmaxf(0.f, acc[i][r] + bb);
                }
            }
        }
        __syncthreads();
    }

    // ---- pred = p2 @ W5 + b5, then rotate + residual
    if (tid < 96) {
        int o = tid >> 4, sl = tid & 15, kb = sl * 8;
        float w5[8];
#pragma unroll
        for (int j = 0; j < 8; ++j) w5[j] = W5[(kb + j) * IN + o];
#pragma unroll
        for (int g = 0; g < G; ++g) {
            float s = 0.f;
#pragma unroll
            for (int j = 0; j < 8; ++j) s = fmaf(xFp[g * 132 + kb + j], w5[j], s);
            pbF[g * 96 + sl * 6 + o] = s;
        }
    }
    __syncthreads();
    if (tid < 24) {
        int g = tid / 6, o = tid - g * 6;
        float s = b5[o];
#pragma unroll
        for (int sl = 0; sl < 16; ++sl) s += pbF[g * 96 + sl * 6 + o];
        predF[g * 8 + o] = s;
    }
    __syncthreads();
    if (tid < 24) {
        int g = tid / 6, o = tid - g * 6;
        int r = (o < 3) ? o : o - 3;
        int off = (o < 3) ? 0 : 3;
        const float* Rg = sxr + (n0 + g) * SXS;
        float gl = Rg[r * 3 + 0] * predF[g * 8 + off + 0]
                 + Rg[r * 3 + 1] * predF[g * 8 + off + 1]
                 + Rg[r * 3 + 2] * predF[g * 8 + off + 2];
        int bng = bn0 + g;
        out[bng * IN + o] = Rg[9 + o] + gl;      // in[bng*6+o] == sxr pos/vel
    }
}

extern "C" void kernel_launch(void* const* d_in, const int* in_sizes, int n_in,
                              void* d_out, int out_size, void* d_ws, size_t ws_size,
                              hipStream_t stream) {
    const float* in = (const float*)d_in[0];
    const float* W1 = (const float*)d_in[1];
    const float* b1 = (const float*)d_in[2];
    const float* W2 = (const float*)d_in[3];
    const float* b2 = (const float*)d_in[4];
    const float* Wr = (const float*)d_in[5];
    const float* br = (const float*)d_in[6];
    const float* W3 = (const float*)d_in[7];
    const float* b3 = (const float*)d_in[8];
    const float* W4 = (const float*)d_in[9];
    const float* b4 = (const float*)d_in[10];
    const float* W5 = (const float*)d_in[11];
    const float* b5 = (const float*)d_in[12];
    float* out = (float*)d_out;

    half4* w1f  = (half4*)d_ws;                         // 4 KB
    half8* wmlp = (half8*)((char*)d_ws + 4096);         // 96 KB

    const int BN = in_sizes[0] / IN;   // B*N = 12800
    conv_w<<<26, 256, 0, stream>>>(W1, W2, W3, W4, w1f, wmlp);
    locs_fused<<<BN / G, 128, 0, stream>>>(in, W1, b1, b2, Wr, br, b3, b4,
                                           W5, b5, w1f, wmlp, out);
}

// Round 15
// 139.985 us; speedup vs baseline: 1.1658x; 1.0200x over previous
//
#include <hip/hip_runtime.h>
#include <math.h>

#define EPSF 1e-7f
constexpr int NN  = 100;   // nodes per graph
constexpr int DEG = 99;    // fully-connected: deg = NN-1
constexpr int IN  = 6;
constexpr int H   = 128;
constexpr int G   = 4;     // nodes per block
constexpr float INV_PI = 0.3183098861837907f;
constexpr float LOG2E  = 1.4426950408889634f;
constexpr float LN2    = 0.6931471805599453f;

typedef __attribute__((ext_vector_type(4))) _Float16 half4;
typedef __attribute__((ext_vector_type(8))) _Float16 half8;
typedef __attribute__((ext_vector_type(4))) float f32x4;

constexpr int XST = 144;   // fp16 staging stride (288B rows: 16B-aligned)
constexpr int SXS = 15;    // sxr stride in floats: gcd(15,32)=1 -> conflict-free
constexpr int TS  = 50;    // compact tile stride in half4: 48 live + zero slot @48
constexpr int NT  = 25;    // 25 tiles = 4 nodes x (99 edges + 1 pad) exactly

__device__ __forceinline__ float clampf(float x, float lo, float hi) {
    return fminf(fmaxf(x, lo), hi);
}
// sigmoid in exp2-space: input y = x*log2e, sig = 1/(1+2^-y)
__device__ __forceinline__ float sig2(float y) {
    return __builtin_amdgcn_rcpf(1.f + __builtin_amdgcn_exp2f(-y));
}
// fast atan2: octant-reduced deg-7 minimax (~1e-5 rad; features are fp16)
__device__ __forceinline__ float fast_atan2(float y, float x) {
    float ax = fabsf(x), ay = fabsf(y);
    float mx = fmaxf(ax, ay), mn = fminf(ax, ay);
    float r = mn * __builtin_amdgcn_rcpf(fmaxf(mx, 1e-35f));
    float r2 = r * r;
    float p = fmaf(r2, -0.0851330f, 0.1801410f);
    p = fmaf(r2, p, -0.3302995f);
    p = fmaf(r2, p, 0.9998660f);
    float t = r * p;
    t = (ay > ax) ? (1.5707963267948966f - t) : t;
    t = (x < 0.f) ? (3.14159265358979323f - t) : t;
    return copysignf(t, y);
}
__device__ __forceinline__ float fast_asin(float z) {
    return fast_atan2(z, sqrtf(fmaxf(0.f, (1.f - z) * (1.f + z))));
}
__device__ __forceinline__ float fast_acos(float z) {
    return fast_atan2(sqrtf(fmaxf(0.f, (1.f - z) * (1.f + z))), z);
}
__device__ __forceinline__ void vel_to_R(float vx, float vy, float vz, float* R) {
    float rho = sqrtf(vx * vx + vy * vy + vz * vz);
    float rxy = sqrtf(vx * vx + vy * vy);
    float inv = __builtin_amdgcn_rcpf(rxy);
    bool big = rxy > 1e-30f;
    float ct = big ? vx * inv : 1.f;
    float st = big ? vy * inv : 0.f;
    float cp = clampf(vz * __builtin_amdgcn_rcpf(rho + EPSF), -1.f, 1.f);
    float sp = sqrtf(fmaxf(0.f, 1.f - cp * cp));
    R[0] = cp * ct; R[1] = -st; R[2] = sp * ct;
    R[3] = cp * st; R[4] = ct;  R[5] = sp * st;
    R[6] = -sp;     R[7] = 0.f; R[8] = cp;
}

// ---------------- Kernel A: weights -> fp16 MFMA fragments in ws.
// W1 pre-scaled by log2e (silu in exp2 space); W2 pre-scaled by ln2 to undo.
__global__ void conv_w(const float* __restrict__ W1, const float* __restrict__ W2,
                       const float* __restrict__ W3, const float* __restrict__ W4,
                       half4* __restrict__ w1f, half8* __restrict__ wmlp) {
    int t = blockIdx.x * blockDim.x + threadIdx.x;
    if (t >= 104 * 64) return;
    int L = t & 63, f = t >> 6;
    int m = L & 15, qd = L >> 4;
    if (f < 8) {                          // W1 fragments (K=16, k<12 live)
        int n = f * 16 + m;
        half4 v;
#pragma unroll
        for (int j = 0; j < 4; ++j) {
            int k = qd * 4 + j;
            v[j] = (k < 12) ? (_Float16)(W1[k * H + n] * LOG2E) : (_Float16)0.f;
        }
        w1f[f * 64 + L] = v;
    } else {                              // node-MLP weight fragments (K=32)
        int ff = f - 8;
        int layer = ff >> 5, rest = ff & 31;
        int kt = rest >> 3, nt = rest & 7;
        const float* W = (layer == 0) ? W2 : (layer == 1) ? W3 : W4;
        float scale = (layer == 0) ? LN2 : 1.f;
        int n = nt * 16 + m;
        half8 v;
#pragma unroll
        for (int j = 0; j < 8; ++j)
            v[j] = (_Float16)(W[(kt * 32 + qd * 8 + j) * H + n] * scale);
        wmlp[((layer * 4 + kt) * 8 + nt) * 64 + L] = v;
    }
}

// ---------------- Kernel B: fully fused LoCS layer. One block = 4 nodes.
// R15: memory-level parallelism. (1) node-MLP weight fragments batched 16-wide
// before the MFMA chain; (2) bias-fold global loads issued before the producer
// (latency hidden under feature jobs); (3) consumer tile loop software-
// pipelined (prefetch A[t+1] during MFMA+silu of t). Race fix: barrier after
// cvF before any cross-wave read.
__global__ __launch_bounds__(128)
void locs_fused(const float* __restrict__ in,
                const float* __restrict__ W1, const float* __restrict__ b1,
                const float* __restrict__ b2,
                const float* __restrict__ Wr, const float* __restrict__ br,
                const float* __restrict__ b3, const float* __restrict__ b4,
                const float* __restrict__ W5, const float* __restrict__ b5,
                const half4* __restrict__ w1f, const half8* __restrict__ wmlp,
                float* __restrict__ out) {
    __shared__ _Float16 hpool[NT * TS * 4];      // arena (10 KB); reused as xh staging
    __shared__ float sxr[NN * SXS];              // per-node R(9)+pos(3)+vel(3)
    __shared__ float xFp[G * 132];               // fp32 activations (padded stride)
    __shared__ float cvF[16];                    // canon_vel per node
    __shared__ float pbF[G * 96];                // W5 partials
    __shared__ float predF[G * 8];

    const int tid = threadIdx.x;
    const int L   = tid & 63;
    const int wv  = tid >> 6;
    const int q   = L >> 4;                      // lane quad == owned node / kslot
    const int lm  = L & 15;
    const int bn0 = blockIdx.x * G;
    const int bB  = bn0 / NN;                    // same graph for all 4 nodes
    const int n0  = bn0 - bB * NN;

    // ---- setup: zero arena (pad rows / zero slots stay zero all launch)
    {
        half4 z = {0, 0, 0, 0};
        for (int i = tid; i < NT * TS; i += 128) *(half4*)&hpool[i * 4] = z;
    }
    // per-graph-node table (one vel_to_R per node, stride 15 = conflict-free)
    if (tid < NN) {
        const float* xi = in + (bB * NN + tid) * IN;
        float R[9];
        float px = xi[0], py = xi[1], pz = xi[2];
        float vx = xi[3], vy = xi[4], vz = xi[5];
        vel_to_R(vx, vy, vz, R);
        float* dst = sxr + tid * SXS;
#pragma unroll
        for (int k = 0; k < 9; ++k) dst[k] = R[k];
        dst[9] = px; dst[10] = py; dst[11] = pz;
        dst[12] = vx; dst[13] = vy; dst[14] = vz;
    }
    __syncthreads();
    if (tid < G) {                               // canon_vel for the 4 nodes
        const float* rg = sxr + (n0 + tid) * SXS;
        float vx = rg[12], vy = rg[13], vz = rg[14];
        cvF[tid * 4 + 0] = rg[0] * vx + rg[3] * vy + rg[6] * vz;
        cvF[tid * 4 + 1] = rg[1] * vx + rg[4] * vy + rg[7] * vz;
        cvF[tid * 4 + 2] = rg[2] * vx + rg[5] * vy + rg[8] * vz;
    }
    __syncthreads();                             // cvF visible to all waves

    // in-register folded silu bias (exp2 space) — issued BEFORE the producer so
    // the ~16 global loads' latency hides under the feature jobs
    float bs[4];
    {
        float cv0 = cvF[q * 4 + 0], cv1 = cvF[q * 4 + 1], cv2 = cvF[q * 4 + 2];
#pragma unroll
        for (int i = 0; i < 4; ++i) {
            int ch = wv * 64 + i * 16 + lm;
            bs[i] = (b1[ch] + cv0 * W1[15 * H + ch] + cv1 * W1[16 * H + ch]
                   + cv2 * W1[17 * H + ch]) * LOG2E;
        }
    }
    // W1 B-fragments (this wave's 4 channel-tiles)
    half4 bfr[4];
#pragma unroll
    for (int i = 0; i < 4; ++i) bfr[i] = w1f[(wv * 4 + i) * 64 + L];

    // ---- dense producer: all 4 nodes' edge features, packed compact layout
#pragma unroll
    for (int rnd = 0; rnd < 4; ++rnd) {
        int j = tid + rnd * 128;
        if (j < G * DEG) {
            int g = j / DEG;                     // owning node 0..3
            int e = j - g * DEG;                 // edge index 0..98
            int nG = n0 + g;
            int s = e < nG ? e : e + 1;          // implicit ~eye edge list
            const float* rn = sxr + nG * SXS;
            const float* rs = sxr + s * SXS;     // stride-15: conflict-free
            float Rn[9];
#pragma unroll
            for (int k = 0; k < 9; ++k) Rn[k] = rn[k];
            float rel0 = rs[9] - rn[9], rel1 = rs[10] - rn[10], rel2 = rs[11] - rn[11];
            float vjx = rs[12], vjy = rs[13], vjz = rs[14];
            float Rs0 = rs[0], Rs1 = rs[1], Rs2 = rs[2];
            float Rs3 = rs[3], Rs4 = rs[4], Rs5 = rs[5];
            float Rs6 = rs[6], Rs7 = rs[7], Rs8 = rs[8];
            float rr0 = Rn[0] * rel0 + Rn[3] * rel1 + Rn[6] * rel2;
            float rr1 = Rn[1] * rel0 + Rn[4] * rel1 + Rn[7] * rel2;
            float rr2 = Rn[2] * rel0 + Rn[5] * rel1 + Rn[8] * rel2;
            float ro00 = Rn[0] * Rs0 + Rn[3] * Rs3 + Rn[6] * Rs6;
            float ro10 = Rn[1] * Rs0 + Rn[4] * Rs3 + Rn[7] * Rs6;
            float ro20 = Rn[2] * Rs0 + Rn[5] * Rs3 + Rn[8] * Rs6;
            float ro21 = Rn[2] * Rs1 + Rn[5] * Rs4 + Rn[8] * Rs7;
            float ro22 = Rn[2] * Rs2 + Rn[5] * Rs5 + Rn[8] * Rs8;
            float dist = sqrtf(rel0 * rel0 + rel1 * rel1 + rel2 * rel2);
            half4 f0, f1, f2;
            f0[0] = (_Float16)rr0; f0[1] = (_Float16)rr1; f0[2] = (_Float16)rr2;
            f0[3] = (_Float16)(fast_atan2(ro10, ro00) * INV_PI);
            f1[0] = (_Float16)(fast_asin(clampf(-ro20, -1.f, 1.f)) * INV_PI);
            f1[1] = (_Float16)(fast_atan2(ro21, ro22) * INV_PI);
            f1[2] = (_Float16)dist;              // |rot_rel| == |rel|
            f1[3] = (_Float16)fast_atan2(rr1, rr0);
            f2[0] = (_Float16)fast_acos(clampf(rr2 * __builtin_amdgcn_rcpf(dist + EPSF), -1.f, 1.f));
            f2[1] = (_Float16)(Rn[0] * vjx + Rn[3] * vjy + Rn[6] * vjz);
            f2[2] = (_Float16)(Rn[1] * vjx + Rn[4] * vjy + Rn[7] * vjz);
            f2[3] = (_Float16)(Rn[2] * vjx + Rn[5] * vjy + Rn[8] * vjz);
            int t = e >> 2;                      // tile
            int mrow = g * 4 + (e & 3);          // A row: node quad + edge%4
            _Float16* dst = hpool + (t * TS + mrow) * 4;
            *(half4*)(dst +   0)      = f0;      // kslot 0
            *(half4*)(dst + 16 * 4)   = f1;      // kslot 1
            *(half4*)(dst + 32 * 4)   = f2;      // kslot 2 (kslot 3 = zeros)
        }
    }
    __syncthreads();

    // ---- consumer: uniform 25-tile MFMA + silu, SOFTWARE-PIPELINED
    {
        float part[4] = {0.f, 0.f, 0.f, 0.f};
        f32x4 c[4];
#pragma unroll
        for (int i = 0; i < 4; ++i) c[i] = (f32x4){bs[i], bs[i], bs[i], bs[i]};
        const int loff = (q < 3) ? (q * 16 + lm) : 48;   // qd==3 -> zero slot
        half4 a_cur = *(const half4*)&hpool[(0 * TS + loff) * 4];
#pragma unroll
        for (int t = 0; t < NT; ++t) {
            half4 a_next;
            if (t < NT - 1) a_next = *(const half4*)&hpool[((t + 1) * TS + loff) * 4];
            f32x4 d0 = __builtin_amdgcn_mfma_f32_16x16x16f16(a_cur, bfr[0], c[0], 0, 0, 0);
            f32x4 d1 = __builtin_amdgcn_mfma_f32_16x16x16f16(a_cur, bfr[1], c[1], 0, 0, 0);
            f32x4 d2 = __builtin_amdgcn_mfma_f32_16x16x16f16(a_cur, bfr[2], c[2], 0, 0, 0);
            f32x4 d3 = __builtin_amdgcn_mfma_f32_16x16x16f16(a_cur, bfr[3], c[3], 0, 0, 0);
#pragma unroll
            for (int r = 0; r < 4; ++r) {
                part[0] += d0[r] * sig2(d0[r]);
                part[1] += d1[r] * sig2(d1[r]);
                part[2] += d2[r] * sig2(d2[r]);
                part[3] += d3[r] * sig2(d3[r]);
            }
            a_cur = a_next;
        }
        // exactly one pad element per node (t=24, r=3): cancel uniformly
#pragma unroll
        for (int i = 0; i < 4; ++i)
            xFp[q * 132 + wv * 64 + i * 16 + lm] = part[i] - bs[i] * sig2(bs[i]);
    }
    __syncthreads();

    // ---- node MLP: 3 layers, fp16 MFMA; 16 weight loads batched per layer
    _Float16* xh = hpool;
#pragma unroll
    for (int layer = 0; layer < 3; ++layer) {
#pragma unroll
        for (int r = 0; r < G; ++r)
            xh[r * XST + tid] = (_Float16)xFp[r * 132 + tid];
        // batch ALL 16 fragment loads (independent -> 16 outstanding L2 reqs)
        half8 bh[16];
#pragma unroll
        for (int kt = 0; kt < 4; ++kt) {
            int base = ((layer * 4 + kt) * 8 + wv * 4) * 64 + L;
#pragma unroll
            for (int i = 0; i < 4; ++i) bh[kt * 4 + i] = wmlp[base + i * 64];
        }
        __syncthreads();
        int rowb = (lm & 3) * XST;        // rows 4..15 read dup rows (unread D rows)
        half8 ah[4];
#pragma unroll
        for (int kt = 0; kt < 4; ++kt)
            ah[kt] = *(const half8*)&xh[rowb + kt * 32 + q * 8];
        f32x4 acc[4];
#pragma unroll
        for (int i = 0; i < 4; ++i) acc[i] = (f32x4){0.f, 0.f, 0.f, 0.f};
#pragma unroll
        for (int kt = 0; kt < 4; ++kt)
#pragma unroll
            for (int i = 0; i < 4; ++i)
                acc[i] = __builtin_amdgcn_mfma_f32_16x16x32_f16(ah[kt], bh[kt * 4 + i],
                                                                acc[i], 0, 0, 0);
        __syncthreads();                  // xh reads done; xFp safe to rewrite
        if (L < 16) {                     // quad 0 holds rows 0..3 (the 4 nodes)
#pragma unroll
            for (int i = 0; i < 4; ++i) {
                int ch = wv * 64 + i * 16 + lm;
                if (layer == 0) {
                    float b2c = b2[ch], brc = br[ch];
                    float w3c = Wr[3 * H + ch], w4c = Wr[4 * H + ch], w5c = Wr[5 * H + ch];
#pragma unroll
                    for (int r = 0; r < 4; ++r)
                        xFp[r * 132 + ch] = acc[i][r] * (1.f / 99.f) + b2c
                                          + cvF[r * 4 + 0] * w3c + cvF[r * 4 + 1] * w4c
                                          + cvF[r * 4 + 2] * w5c + brc;
                } else {
                    float bb = (layer == 1) ? b3[ch] : b4[ch];
#pragma unroll
                    for (int r = 0; r < 4; ++r)
                        xFp[r * 132 + ch] = fmaxf(0.f, acc[i][r] + bb);
                }
            }
        }
        __syncthreads();
    }

    // ---- pred = p2 @ W5 + b5, then rotate + residual
    if (tid < 96) {
        int o = tid >> 4, sl = tid & 15, kb = sl * 8;
        float w5[8];
#pragma unroll
        for (int j = 0; j < 8; ++j) w5[j] = W5[(kb + j) * IN + o];
#pragma unroll
        for (int g = 0; g < G; ++g) {
            float s = 0.f;
#pragma unroll
            for (int j = 0; j < 8; ++j) s = fmaf(xFp[g * 132 + kb + j], w5[j], s);
            pbF[g * 96 + sl * 6 + o] = s;
        }
    }
    __syncthreads();
    if (tid < 24) {
        int g = tid / 6, o = tid - g * 6;
        float s = b5[o];
#pragma unroll
        for (int sl = 0; sl < 16; ++sl) s += pbF[g * 96 + sl * 6 + o];
        predF[g * 8 + o] = s;
    }
    __syncthreads();
    if (tid < 24) {
        int g = tid / 6, o = tid - g * 6;
        int r = (o < 3) ? o : o - 3;
        int off = (o < 3) ? 0 : 3;
        const float* Rg = sxr + (n0 + g) * SXS;
        float gl = Rg[r * 3 + 0] * predF[g * 8 + off + 0]
                 + Rg[r * 3 + 1] * predF[g * 8 + off + 1]
                 + Rg[r * 3 + 2] * predF[g * 8 + off + 2];
        int bng = bn0 + g;
        out[bng * IN + o] = Rg[9 + o] + gl;      // in[bng*6+o] == sxr pos/vel
    }
}

extern "C" void kernel_launch(void* const* d_in, const int* in_sizes, int n_in,
                              void* d_out, int out_size, void* d_ws, size_t ws_size,
                              hipStream_t stream) {
    const float* in = (const float*)d_in[0];
    const float* W1 = (const float*)d_in[1];
    const float* b1 = (const float*)d_in[2];
    const float* W2 = (const float*)d_in[3];
    const float* b2 = (const float*)d_in[4];
    const float* Wr = (const float*)d_in[5];
    const float* br = (const float*)d_in[6];
    const float* W3 = (const float*)d_in[7];
    const float* b3 = (const float*)d_in[8];
    const float* W4 = (const float*)d_in[9];
    const float* b4 = (const float*)d_in[10];
    const float* W5 = (const float*)d_in[11];
    const float* b5 = (const float*)d_in[12];
    float* out = (float*)d_out;

    half4* w1f  = (half4*)d_ws;                         // 4 KB
    half8* wmlp = (half8*)((char*)d_ws + 4096);         // 96 KB

    const int BN = in_sizes[0] / IN;   // B*N = 12800
    conv_w<<<26, 256, 0, stream>>>(W1, W2, W3, W4, w1f, wmlp);
    locs_fused<<<BN / G, 128, 0, stream>>>(in, W1, b1, b2, Wr, br, b3, b4,
                                           W5, b5, w1f, wmlp, out);
}